// Round 1
// baseline (525.912 us; speedup 1.0000x reference)
//
#include <hip/hip_runtime.h>
#include <hip/hip_bf16.h>

#define NE 8
#define C 1024
#define F 2816
#define LDK 40   // padded LDS row stride in bf16 elements (80B = 16B-aligned, banks spread)

typedef __bf16 bf16_t;
typedef bf16_t bf16x8 __attribute__((ext_vector_type(8)));
typedef float f32x4 __attribute__((ext_vector_type(4)));

__device__ inline unsigned pk2(float a, float b) {
    union { bf16_t h[2]; unsigned u; } x;
    x.h[0] = (bf16_t)a; x.h[1] = (bf16_t)b;
    return x.u;
}

// ---------------- router: fp32 logits, top-2, softmax ----------------
__global__ void router_kernel(const float* __restrict__ x, const float* __restrict__ Wg,
                              float* __restrict__ probs, int* __restrict__ idxbuf,
                              float* __restrict__ out_idx) {
    const int n = blockIdx.x;
    const int lane = threadIdx.x;  // 64 threads = 1 wave
    const float* xr = x + (size_t)n * C;
    float acc[NE] = {0.f, 0.f, 0.f, 0.f, 0.f, 0.f, 0.f, 0.f};
    #pragma unroll
    for (int i = 0; i < C / 64; i++) {
        int c = i * 64 + lane;
        float xv = xr[c];
        const float4* w = (const float4*)(Wg + (size_t)c * NE);
        float4 w0 = w[0], w1 = w[1];
        acc[0] += xv * w0.x; acc[1] += xv * w0.y; acc[2] += xv * w0.z; acc[3] += xv * w0.w;
        acc[4] += xv * w1.x; acc[5] += xv * w1.y; acc[6] += xv * w1.z; acc[7] += xv * w1.w;
    }
    #pragma unroll
    for (int off = 32; off >= 1; off >>= 1)
        #pragma unroll
        for (int e = 0; e < NE; e++) acc[e] += __shfl_down(acc[e], off);
    if (lane == 0) {
        float v0 = -1e30f, v1 = -1e30f; int i0 = 0, i1 = 0;
        #pragma unroll
        for (int e = 0; e < NE; e++) {
            float v = acc[e];
            if (v > v0)      { v1 = v0; i1 = i0; v0 = v; i0 = e; }
            else if (v > v1) { v1 = v; i1 = e; }
        }
        float e1 = __expf(v1 - v0);
        float p0 = 1.0f / (1.0f + e1);
        probs[n * 2]     = p0;
        probs[n * 2 + 1] = e1 / (1.0f + e1);
        idxbuf[n * 2]     = i0;
        idxbuf[n * 2 + 1] = i1;
        out_idx[n * 2]     = (float)i0;   // out buffer is read back as fp32
        out_idx[n * 2 + 1] = (float)i1;
    }
}

// ---------------- group tokens by expert (single block) ----------------
__global__ void group_kernel(const int* __restrict__ idxbuf, int* __restrict__ rowinfo,
                             int* __restrict__ counts, int* __restrict__ offs, int N) {
    __shared__ int cnt[NE], run[NE], base[NE];
    const int t = threadIdx.x;
    if (t < NE) { cnt[t] = 0; run[t] = 0; }
    __syncthreads();
    for (int i = t; i < N * 2; i += blockDim.x) atomicAdd(&cnt[idxbuf[i]], 1);
    __syncthreads();
    if (t == 0) { int s = 0; for (int e = 0; e < NE; e++) { base[e] = s; s += cnt[e]; } }
    __syncthreads();
    for (int i = t; i < N * 2; i += blockDim.x) {
        int e = idxbuf[i];
        int p = atomicAdd(&run[e], 1);
        rowinfo[base[e] + p] = i;          // i = n*2 + k
    }
    if (t < NE) { counts[t] = cnt[t]; offs[t] = base[t]; }
}

// ---------------- GEMM1: h = silu(Xg@W1) * (Xg@W3), grouped per expert ----------------
__global__ __launch_bounds__(256, 2)
void gemm1_kernel(const float* __restrict__ x, const float* __restrict__ W1,
                  const float* __restrict__ W3, const int* __restrict__ rowinfo,
                  const int* __restrict__ counts, const int* __restrict__ offs,
                  bf16_t* __restrict__ hbuf) {
    const int e = blockIdx.z;
    const int cnt = counts[e];
    const int m0 = blockIdx.y * 128;
    if (m0 >= cnt) return;
    const int base = offs[e];
    const int f0 = blockIdx.x * 128;
    const int t = threadIdx.x;
    const int lane = t & 63, wave = t >> 6;
    const int wm = (wave >> 1) * 64, wn = (wave & 1) * 64;
    const int lr = lane & 15, quad = lane >> 4;

    __shared__ __align__(16) bf16_t As[128 * LDK];
    __shared__ __align__(16) bf16_t B1s[128 * LDK];
    __shared__ __align__(16) bf16_t B3s[128 * LDK];

    // A staging: thread -> (row, half-of-32k)
    const int am = t >> 1;
    const int ak = (t & 1) * 16;
    const int tok = rowinfo[base + min(m0 + am, cnt - 1)] >> 1;
    const float* aptr = x + (size_t)tok * C + ak;

    // B staging: thread -> (f column, 8-k group); coalesced per-k loads, transposed LDS write
    const int bf = t & 127;
    const int bk0 = (t >> 7) * 8;  // 0 or 8; +16 on second pass
    const float* b1ptr = W1 + (size_t)e * C * F + f0 + bf;
    const float* b3ptr = W3 + (size_t)e * C * F + f0 + bf;

    f32x4 acc1[4][4], acc3[4][4];
    const f32x4 zero = {0.f, 0.f, 0.f, 0.f};
    #pragma unroll
    for (int im = 0; im < 4; im++)
        #pragma unroll
        for (int in = 0; in < 4; in++) { acc1[im][in] = zero; acc3[im][in] = zero; }

    for (int kc = 0; kc < C; kc += 32) {
        const float4* ap = (const float4*)(aptr + kc);
        float4 a0 = ap[0], a1 = ap[1], a2 = ap[2], a3 = ap[3];
        uint4 av0 = make_uint4(pk2(a0.x, a0.y), pk2(a0.z, a0.w), pk2(a1.x, a1.y), pk2(a1.z, a1.w));
        uint4 av1 = make_uint4(pk2(a2.x, a2.y), pk2(a2.z, a2.w), pk2(a3.x, a3.y), pk2(a3.z, a3.w));
        *(uint4*)(&As[am * LDK + ak])     = av0;
        *(uint4*)(&As[am * LDK + ak + 8]) = av1;
        #pragma unroll
        for (int g = 0; g < 2; g++) {
            const int kk = kc + bk0 + g * 16;
            const float* p1 = b1ptr + (size_t)kk * F;
            float v[8];
            #pragma unroll
            for (int i = 0; i < 8; i++) v[i] = p1[(size_t)i * F];
            uint4 bv1 = make_uint4(pk2(v[0], v[1]), pk2(v[2], v[3]), pk2(v[4], v[5]), pk2(v[6], v[7]));
            *(uint4*)(&B1s[bf * LDK + bk0 + g * 16]) = bv1;
            const float* p3 = b3ptr + (size_t)kk * F;
            #pragma unroll
            for (int i = 0; i < 8; i++) v[i] = p3[(size_t)i * F];
            uint4 bv3 = make_uint4(pk2(v[0], v[1]), pk2(v[2], v[3]), pk2(v[4], v[5]), pk2(v[6], v[7]));
            *(uint4*)(&B3s[bf * LDK + bk0 + g * 16]) = bv3;
        }
        __syncthreads();
        bf16x8 af[4], b1f[4], b3f[4];
        #pragma unroll
        for (int im = 0; im < 4; im++)
            af[im] = *(const bf16x8*)(&As[(wm + im * 16 + lr) * LDK + quad * 8]);
        #pragma unroll
        for (int in = 0; in < 4; in++) {
            b1f[in] = *(const bf16x8*)(&B1s[(wn + in * 16 + lr) * LDK + quad * 8]);
            b3f[in] = *(const bf16x8*)(&B3s[(wn + in * 16 + lr) * LDK + quad * 8]);
        }
        #pragma unroll
        for (int im = 0; im < 4; im++)
            #pragma unroll
            for (int in = 0; in < 4; in++) {
                acc1[im][in] = __builtin_amdgcn_mfma_f32_16x16x32_bf16(af[im], b1f[in], acc1[im][in], 0, 0, 0);
                acc3[im][in] = __builtin_amdgcn_mfma_f32_16x16x32_bf16(af[im], b3f[in], acc3[im][in], 0, 0, 0);
            }
        __syncthreads();
    }
    // epilogue: h = silu(h1)*h3 -> bf16 hbuf rows
    #pragma unroll
    for (int im = 0; im < 4; im++) {
        #pragma unroll
        for (int r = 0; r < 4; r++) {
            const int row = wm + im * 16 + quad * 4 + r;
            const int gi = m0 + row;
            if (gi < cnt) {
                bf16_t* hp = hbuf + (size_t)(base + gi) * F + f0 + wn + lr;
                #pragma unroll
                for (int in = 0; in < 4; in++) {
                    float h1 = acc1[im][in][r], h3 = acc3[im][in][r];
                    float s = h1 / (1.0f + __expf(-h1)) * h3;
                    hp[in * 16] = (bf16_t)s;
                }
            }
        }
    }
}

// ---------------- GEMM2: contrib[slot] = h @ W2[e] ----------------
__global__ __launch_bounds__(256, 2)
void gemm2_kernel(const bf16_t* __restrict__ hbuf, const float* __restrict__ W2,
                  const int* __restrict__ rowinfo, const int* __restrict__ counts,
                  const int* __restrict__ offs, float* __restrict__ contrib) {
    const int e = blockIdx.z;
    const int cnt = counts[e];
    const int m0 = blockIdx.y * 128;
    if (m0 >= cnt) return;
    const int base = offs[e];
    const int c0 = blockIdx.x * 128;
    const int t = threadIdx.x;
    const int lane = t & 63, wave = t >> 6;
    const int wm = (wave >> 1) * 64, wn = (wave & 1) * 64;
    const int lr = lane & 15, quad = lane >> 4;

    __shared__ __align__(16) bf16_t As[128 * LDK];
    __shared__ __align__(16) bf16_t Bs[128 * LDK];

    const int am = t >> 1;
    const int ak = (t & 1) * 16;
    const bf16_t* aptr = hbuf + (size_t)(base + min(m0 + am, cnt - 1)) * F + ak;

    const int bfc = t & 127;
    const int bk0 = (t >> 7) * 8;
    const float* bptr = W2 + (size_t)e * F * C + c0 + bfc;

    f32x4 acc[4][4];
    const f32x4 zero = {0.f, 0.f, 0.f, 0.f};
    #pragma unroll
    for (int im = 0; im < 4; im++)
        #pragma unroll
        for (int in = 0; in < 4; in++) acc[im][in] = zero;

    for (int kc = 0; kc < F; kc += 32) {
        const uint4* ap = (const uint4*)(aptr + kc);
        *(uint4*)(&As[am * LDK + ak])     = ap[0];
        *(uint4*)(&As[am * LDK + ak + 8]) = ap[1];
        #pragma unroll
        for (int g = 0; g < 2; g++) {
            const int kk = kc + bk0 + g * 16;
            const float* p = bptr + (size_t)kk * C;
            float v[8];
            #pragma unroll
            for (int i = 0; i < 8; i++) v[i] = p[(size_t)i * C];
            uint4 bv = make_uint4(pk2(v[0], v[1]), pk2(v[2], v[3]), pk2(v[4], v[5]), pk2(v[6], v[7]));
            *(uint4*)(&Bs[bfc * LDK + bk0 + g * 16]) = bv;
        }
        __syncthreads();
        bf16x8 af[4], bf_[4];
        #pragma unroll
        for (int im = 0; im < 4; im++)
            af[im] = *(const bf16x8*)(&As[(wm + im * 16 + lr) * LDK + quad * 8]);
        #pragma unroll
        for (int in = 0; in < 4; in++)
            bf_[in] = *(const bf16x8*)(&Bs[(wn + in * 16 + lr) * LDK + quad * 8]);
        #pragma unroll
        for (int im = 0; im < 4; im++)
            #pragma unroll
            for (int in = 0; in < 4; in++)
                acc[im][in] = __builtin_amdgcn_mfma_f32_16x16x32_bf16(af[im], bf_[in], acc[im][in], 0, 0, 0);
        __syncthreads();
    }
    #pragma unroll
    for (int im = 0; im < 4; im++) {
        #pragma unroll
        for (int r = 0; r < 4; r++) {
            const int row = wm + im * 16 + quad * 4 + r;
            const int gi = m0 + row;
            if (gi < cnt) {
                const int slot = rowinfo[base + gi];
                float* cp = contrib + (size_t)slot * C + c0 + wn + lr;
                #pragma unroll
                for (int in = 0; in < 4; in++) cp[in * 16] = acc[im][in][r];
            }
        }
    }
}

// ---------------- combine: y = p0*contrib[2n] + p1*contrib[2n+1] ----------------
__global__ void combine_kernel(const float* __restrict__ contrib, const float* __restrict__ probs,
                               float* __restrict__ y) {
    const int idx = blockIdx.x * blockDim.x + threadIdx.x;  // one float4 per thread
    const int n = idx >> 8;           // 256 float4 per row (C=1024)
    const int c = (idx & 255) * 4;
    const float p0 = probs[n * 2], p1 = probs[n * 2 + 1];
    const float4 a = *(const float4*)(contrib + ((size_t)n * 2) * C + c);
    const float4 b = *(const float4*)(contrib + ((size_t)n * 2 + 1) * C + c);
    float4 o;
    o.x = p0 * a.x + p1 * b.x;
    o.y = p0 * a.y + p1 * b.y;
    o.z = p0 * a.z + p1 * b.z;
    o.w = p0 * a.w + p1 * b.w;
    *(float4*)(y + (size_t)n * C + c) = o;
}

extern "C" void kernel_launch(void* const* d_in, const int* in_sizes, int n_in,
                              void* d_out, int out_size, void* d_ws, size_t ws_size,
                              hipStream_t stream) {
    const float* x  = (const float*)d_in[0];
    const float* Wg = (const float*)d_in[1];
    const float* W1 = (const float*)d_in[2];
    const float* W3 = (const float*)d_in[3];
    const float* W2 = (const float*)d_in[4];
    const int N = in_sizes[0] / C;  // 2048

    float* y = (float*)d_out;
    float* out_idx = y + (size_t)N * C;

    char* ws = (char*)d_ws;
    float* probs  = (float*)ws;                       // N*2 floats
    int* idxbuf   = (int*)(ws + (size_t)N * 2 * 4);   // N*2 ints
    int* rowinfo  = (int*)(ws + (size_t)N * 4 * 4);   // N*2 ints
    int* counts   = (int*)(ws + (size_t)N * 6 * 4);   // 8 ints
    int* offs     = (int*)(ws + (size_t)N * 6 * 4 + 64);
    size_t hoff = ((size_t)N * 6 * 4 + 1024 + 255) & ~(size_t)255;
    bf16_t* hbuf = (bf16_t*)(ws + hoff);              // (N*2) x F bf16
    size_t coff = (hoff + (size_t)N * 2 * F * 2 + 255) & ~(size_t)255;
    float* contrib = (float*)(ws + coff);             // (N*2) x C fp32

    const int mtiles = (N + 127) / 128;

    router_kernel<<<N, 64, 0, stream>>>(x, Wg, probs, idxbuf, out_idx);
    group_kernel<<<1, 256, 0, stream>>>(idxbuf, rowinfo, counts, offs, N);
    gemm1_kernel<<<dim3(F / 128, mtiles, NE), 256, 0, stream>>>(x, W1, W3, rowinfo, counts, offs, hbuf);
    gemm2_kernel<<<dim3(C / 128, mtiles, NE), 256, 0, stream>>>(hbuf, W2, rowinfo, counts, offs, contrib);
    combine_kernel<<<(N * C / 4 + 255) / 256, 256, 0, stream>>>(contrib, probs, y);
}

// Round 2
// 455.275 us; speedup vs baseline: 1.1552x; 1.1552x over previous
//
#include <hip/hip_runtime.h>
#include <hip/hip_bf16.h>

#define NE 8
#define C 1024
#define F 2816

typedef __bf16 bf16_t;
typedef bf16_t bf16x8 __attribute__((ext_vector_type(8)));
typedef float f32x4 __attribute__((ext_vector_type(4)));

__device__ inline unsigned pk2(float a, float b) {
    union { bf16_t h[2]; unsigned u; } x;
    x.h[0] = (bf16_t)a; x.h[1] = (bf16_t)b;
    return x.u;
}

// async global->LDS, 16 B per lane; lds base must be wave-uniform
__device__ __forceinline__ void async_ld16(const bf16_t* g, bf16_t* l) {
    __builtin_amdgcn_global_load_lds(
        (const __attribute__((address_space(1))) unsigned int*)g,
        (__attribute__((address_space(3))) unsigned int*)l, 16, 0, 0);
}

// ---------------- router: fp32 logits, top-2, softmax; also emits bf16 x ----------------
__global__ void router_kernel(const float* __restrict__ x, const float* __restrict__ Wg,
                              float* __restrict__ probs, int* __restrict__ idxbuf,
                              float* __restrict__ out_idx, bf16_t* __restrict__ xb) {
    const int n = blockIdx.x;
    const int lane = threadIdx.x;  // 64 threads = 1 wave
    const float* xr = x + (size_t)n * C;
    bf16_t* xbr = xb + (size_t)n * C;
    float acc[NE] = {0.f, 0.f, 0.f, 0.f, 0.f, 0.f, 0.f, 0.f};
    #pragma unroll
    for (int i = 0; i < C / 64; i++) {
        int c = i * 64 + lane;
        float xv = xr[c];
        xbr[c] = (bf16_t)xv;
        const float4* w = (const float4*)(Wg + (size_t)c * NE);
        float4 w0 = w[0], w1 = w[1];
        acc[0] += xv * w0.x; acc[1] += xv * w0.y; acc[2] += xv * w0.z; acc[3] += xv * w0.w;
        acc[4] += xv * w1.x; acc[5] += xv * w1.y; acc[6] += xv * w1.z; acc[7] += xv * w1.w;
    }
    #pragma unroll
    for (int off = 32; off >= 1; off >>= 1)
        #pragma unroll
        for (int e = 0; e < NE; e++) acc[e] += __shfl_down(acc[e], off);
    if (lane == 0) {
        float v0 = -1e30f, v1 = -1e30f; int i0 = 0, i1 = 0;
        #pragma unroll
        for (int e = 0; e < NE; e++) {
            float v = acc[e];
            if (v > v0)      { v1 = v0; i1 = i0; v0 = v; i0 = e; }
            else if (v > v1) { v1 = v; i1 = e; }
        }
        float e1 = __expf(v1 - v0);
        probs[n * 2]     = 1.0f / (1.0f + e1);
        probs[n * 2 + 1] = e1 / (1.0f + e1);
        idxbuf[n * 2]     = i0;
        idxbuf[n * 2 + 1] = i1;
        out_idx[n * 2]     = (float)i0;
        out_idx[n * 2 + 1] = (float)i1;
    }
}

// ---------------- group tokens by expert (single block) ----------------
__global__ void group_kernel(const int* __restrict__ idxbuf, int* __restrict__ rowinfo,
                             int* __restrict__ counts, int* __restrict__ offs, int N) {
    __shared__ int cnt[NE], run[NE], base[NE];
    const int t = threadIdx.x;
    if (t < NE) { cnt[t] = 0; run[t] = 0; }
    __syncthreads();
    for (int i = t; i < N * 2; i += blockDim.x) atomicAdd(&cnt[idxbuf[i]], 1);
    __syncthreads();
    if (t == 0) { int s = 0; for (int e = 0; e < NE; e++) { base[e] = s; s += cnt[e]; } }
    __syncthreads();
    for (int i = t; i < N * 2; i += blockDim.x) {
        int e = idxbuf[i];
        int p = atomicAdd(&run[e], 1);
        rowinfo[base[e] + p] = i;          // i = n*2 + k
    }
    if (t < NE) { counts[t] = cnt[t]; offs[t] = base[t]; }
}

// ---------------- convert + transpose weights: fp32 [R][Cc] -> bf16 [Cc][R] ----------------
__global__ __launch_bounds__(256)
void convert_kernel(const float* __restrict__ W1, const float* __restrict__ W3,
                    const float* __restrict__ W2, bf16_t* __restrict__ Wt1,
                    bf16_t* __restrict__ Wt3, bf16_t* __restrict__ Wt2) {
    const int yy = blockIdx.y;
    const int which = yy >> 3, e = yy & 7;
    const float* src; bf16_t* dst; int R, Cc;
    if (which == 0)      { src = W1; dst = Wt1; R = C; Cc = F; }
    else if (which == 1) { src = W3; dst = Wt3; R = C; Cc = F; }
    else                 { src = W2; dst = Wt2; R = F; Cc = C; }
    src += (size_t)e * C * F;
    dst += (size_t)e * C * F;
    const int tiles_r = R >> 6;
    const int bx = blockIdx.x;
    const int tr = bx % tiles_r, tc = bx / tiles_r;
    const int t = threadIdx.x;
    __shared__ __align__(16) bf16_t tile[64 * 72];

    // load 4x4 fp32 mini-tile, write transposed bf16 into LDS
    const int mr = t >> 4, mc = t & 15;
    const float* sp = src + (size_t)(tr * 64 + mr * 4) * Cc + tc * 64 + mc * 4;
    float4 v0 = *(const float4*)(sp);
    float4 v1 = *(const float4*)(sp + Cc);
    float4 v2 = *(const float4*)(sp + 2 * (size_t)Cc);
    float4 v3 = *(const float4*)(sp + 3 * (size_t)Cc);
    uint2 u;
    u.x = pk2(v0.x, v1.x); u.y = pk2(v2.x, v3.x); *(uint2*)&tile[(mc * 4 + 0) * 72 + mr * 4] = u;
    u.x = pk2(v0.y, v1.y); u.y = pk2(v2.y, v3.y); *(uint2*)&tile[(mc * 4 + 1) * 72 + mr * 4] = u;
    u.x = pk2(v0.z, v1.z); u.y = pk2(v2.z, v3.z); *(uint2*)&tile[(mc * 4 + 2) * 72 + mr * 4] = u;
    u.x = pk2(v0.w, v1.w); u.y = pk2(v2.w, v3.w); *(uint2*)&tile[(mc * 4 + 3) * 72 + mr * 4] = u;
    __syncthreads();
    // store contiguous bf16 rows of the transposed tile
    const int dc = t >> 2, rc = (t & 3) * 16;
    uint4 o0 = *(uint4*)&tile[dc * 72 + rc];
    uint4 o1 = *(uint4*)&tile[dc * 72 + rc + 8];
    bf16_t* dp = dst + (size_t)(tc * 64 + dc) * R + tr * 64 + rc;
    *(uint4*)(dp)     = o0;
    *(uint4*)(dp + 8) = o1;
}

// ---------------- GEMM1: h = silu(Xg@W1) * (Xg@W3), grouped per expert ----------------
__global__ __launch_bounds__(256, 2)
void gemm1_kernel(const bf16_t* __restrict__ xb, const bf16_t* __restrict__ Wt1,
                  const bf16_t* __restrict__ Wt3, const int* __restrict__ rowinfo,
                  const int* __restrict__ counts, const int* __restrict__ offs,
                  bf16_t* __restrict__ hbuf) {
    const int e = blockIdx.z;
    const int cnt = counts[e];
    const int m0 = blockIdx.y << 7;
    if (m0 >= cnt) return;
    const int base = offs[e];
    const int f0 = blockIdx.x << 7;
    const int t = threadIdx.x;
    const int lane = t & 63, w = t >> 6;
    const int lr = lane & 15, quad = lane >> 4;
    const int wm = (w >> 1) << 6, wn = (w & 1) << 6;

    __shared__ __align__(16) bf16_t As[128 * 32];
    __shared__ __align__(16) bf16_t B1s[128 * 32];
    __shared__ __align__(16) bf16_t B3s[128 * 32];

    const int srow = w * 16 + (lane >> 2);   // staging row within 64-row half
    const int skoff = (lane & 3) * 8;        // bf16 elems within 32-k chunk
    const int r0 = min(m0 + srow, cnt - 1);
    const int r1 = min(m0 + 64 + srow, cnt - 1);
    const bf16_t* ag0 = xb + (size_t)(rowinfo[base + r0] >> 1) * C + skoff;
    const bf16_t* ag1 = xb + (size_t)(rowinfo[base + r1] >> 1) * C + skoff;
    const bf16_t* b1g0 = Wt1 + ((size_t)e * F + f0 + srow) * C + skoff;
    const bf16_t* b1g1 = b1g0 + (size_t)64 * C;
    const bf16_t* b3g0 = Wt3 + ((size_t)e * F + f0 + srow) * C + skoff;
    const bf16_t* b3g1 = b3g0 + (size_t)64 * C;
    bf16_t* lA0 = &As[(w * 16) * 32];
    bf16_t* lA1 = &As[(64 + w * 16) * 32];
    bf16_t* lB10 = &B1s[(w * 16) * 32];
    bf16_t* lB11 = &B1s[(64 + w * 16) * 32];
    bf16_t* lB30 = &B3s[(w * 16) * 32];
    bf16_t* lB31 = &B3s[(64 + w * 16) * 32];

    f32x4 acc1[4][4], acc3[4][4];
    const f32x4 zero = {0.f, 0.f, 0.f, 0.f};
    #pragma unroll
    for (int im = 0; im < 4; im++)
        #pragma unroll
        for (int in = 0; in < 4; in++) { acc1[im][in] = zero; acc3[im][in] = zero; }

    for (int kc = 0; kc < C; kc += 32) {
        async_ld16(ag0 + kc, lA0);
        async_ld16(ag1 + kc, lA1);
        async_ld16(b1g0 + kc, lB10);
        async_ld16(b1g1 + kc, lB11);
        async_ld16(b3g0 + kc, lB30);
        async_ld16(b3g1 + kc, lB31);
        __syncthreads();
        bf16x8 af[4], b1f[4], b3f[4];
        #pragma unroll
        for (int im = 0; im < 4; im++)
            af[im] = *(const bf16x8*)(&As[(wm + im * 16 + lr) * 32 + quad * 8]);
        #pragma unroll
        for (int in = 0; in < 4; in++) {
            b1f[in] = *(const bf16x8*)(&B1s[(wn + in * 16 + lr) * 32 + quad * 8]);
            b3f[in] = *(const bf16x8*)(&B3s[(wn + in * 16 + lr) * 32 + quad * 8]);
        }
        #pragma unroll
        for (int im = 0; im < 4; im++)
            #pragma unroll
            for (int in = 0; in < 4; in++) {
                acc1[im][in] = __builtin_amdgcn_mfma_f32_16x16x32_bf16(af[im], b1f[in], acc1[im][in], 0, 0, 0);
                acc3[im][in] = __builtin_amdgcn_mfma_f32_16x16x32_bf16(af[im], b3f[in], acc3[im][in], 0, 0, 0);
            }
        __syncthreads();
    }
    #pragma unroll
    for (int im = 0; im < 4; im++) {
        #pragma unroll
        for (int r = 0; r < 4; r++) {
            const int row = wm + im * 16 + quad * 4 + r;
            const int gi = m0 + row;
            if (gi < cnt) {
                bf16_t* hp = hbuf + (size_t)(base + gi) * F + f0 + wn + lr;
                #pragma unroll
                for (int in = 0; in < 4; in++) {
                    float h1 = acc1[im][in][r], h3 = acc3[im][in][r];
                    float s = h1 / (1.0f + __expf(-h1)) * h3;
                    hp[in * 16] = (bf16_t)s;
                }
            }
        }
    }
}

// ---------------- GEMM2 (split-K): part[ks][slot] = h @ Wt2[e] over K-slice ----------------
__global__ __launch_bounds__(256, 2)
void gemm2_kernel(const bf16_t* __restrict__ hbuf, const bf16_t* __restrict__ Wt2,
                  const int* __restrict__ rowinfo, const int* __restrict__ counts,
                  const int* __restrict__ offs, float* __restrict__ part,
                  int PK, int nslots) {
    const int z = blockIdx.z;
    const int e = z & 7, ks = z >> 3;
    const int cnt = counts[e];
    const int m0 = blockIdx.y << 7;
    if (m0 >= cnt) return;
    const int base = offs[e];
    const int c0 = blockIdx.x << 7;
    const int t = threadIdx.x;
    const int lane = t & 63, w = t >> 6;
    const int lr = lane & 15, quad = lane >> 4;
    const int wm = (w >> 1) << 6, wn = (w & 1) << 6;

    const int klen = F / PK;
    const int kbeg = ks * klen, kend = kbeg + klen;

    __shared__ __align__(16) bf16_t As[128 * 32];
    __shared__ __align__(16) bf16_t Bs[128 * 32];

    const int srow = w * 16 + (lane >> 2);
    const int skoff = (lane & 3) * 8;
    const int r0 = min(m0 + srow, cnt - 1);
    const int r1 = min(m0 + 64 + srow, cnt - 1);
    const bf16_t* ag0 = hbuf + (size_t)(base + r0) * F + skoff;
    const bf16_t* ag1 = hbuf + (size_t)(base + r1) * F + skoff;
    const bf16_t* bg0 = Wt2 + ((size_t)e * C + c0 + srow) * F + skoff;
    const bf16_t* bg1 = bg0 + (size_t)64 * F;
    bf16_t* lA0 = &As[(w * 16) * 32];
    bf16_t* lA1 = &As[(64 + w * 16) * 32];
    bf16_t* lB0 = &Bs[(w * 16) * 32];
    bf16_t* lB1 = &Bs[(64 + w * 16) * 32];

    f32x4 acc[4][4];
    const f32x4 zero = {0.f, 0.f, 0.f, 0.f};
    #pragma unroll
    for (int im = 0; im < 4; im++)
        #pragma unroll
        for (int in = 0; in < 4; in++) acc[im][in] = zero;

    for (int kc = kbeg; kc < kend; kc += 32) {
        async_ld16(ag0 + kc, lA0);
        async_ld16(ag1 + kc, lA1);
        async_ld16(bg0 + kc, lB0);
        async_ld16(bg1 + kc, lB1);
        __syncthreads();
        bf16x8 af[4], bf_[4];
        #pragma unroll
        for (int im = 0; im < 4; im++)
            af[im] = *(const bf16x8*)(&As[(wm + im * 16 + lr) * 32 + quad * 8]);
        #pragma unroll
        for (int in = 0; in < 4; in++)
            bf_[in] = *(const bf16x8*)(&Bs[(wn + in * 16 + lr) * 32 + quad * 8]);
        #pragma unroll
        for (int im = 0; im < 4; im++)
            #pragma unroll
            for (int in = 0; in < 4; in++)
                acc[im][in] = __builtin_amdgcn_mfma_f32_16x16x32_bf16(af[im], bf_[in], acc[im][in], 0, 0, 0);
        __syncthreads();
    }
    #pragma unroll
    for (int im = 0; im < 4; im++) {
        #pragma unroll
        for (int r = 0; r < 4; r++) {
            const int row = wm + im * 16 + quad * 4 + r;
            const int gi = m0 + row;
            if (gi < cnt) {
                const int slot = rowinfo[base + gi];
                float* cp = part + ((size_t)ks * nslots + slot) * C + c0 + wn + lr;
                #pragma unroll
                for (int in = 0; in < 4; in++) cp[in * 16] = acc[im][in][r];
            }
        }
    }
}

// ---------------- reduce partials + combine: y = p0*sum(part[.,2n]) + p1*sum(part[.,2n+1]) ----------------
__global__ void reduce_kernel(const float* __restrict__ part, const float* __restrict__ probs,
                              float* __restrict__ y, int PK, int nslots) {
    const int idx = blockIdx.x * blockDim.x + threadIdx.x;  // one float4 per thread
    const int n = idx >> 8;
    const int c = (idx & 255) * 4;
    const size_t ksstride = (size_t)nslots * C;
    const float* b0 = part + ((size_t)n * 2) * C + c;
    float4 s0 = {0.f, 0.f, 0.f, 0.f}, s1 = {0.f, 0.f, 0.f, 0.f};
    for (int ks = 0; ks < PK; ks++) {
        float4 a = *(const float4*)(b0 + ks * ksstride);
        float4 b = *(const float4*)(b0 + ks * ksstride + C);
        s0.x += a.x; s0.y += a.y; s0.z += a.z; s0.w += a.w;
        s1.x += b.x; s1.y += b.y; s1.z += b.z; s1.w += b.w;
    }
    const float p0 = probs[n * 2], p1 = probs[n * 2 + 1];
    float4 o;
    o.x = p0 * s0.x + p1 * s1.x;
    o.y = p0 * s0.y + p1 * s1.y;
    o.z = p0 * s0.z + p1 * s1.z;
    o.w = p0 * s0.w + p1 * s1.w;
    *(float4*)(y + (size_t)n * C + c) = o;
}

extern "C" void kernel_launch(void* const* d_in, const int* in_sizes, int n_in,
                              void* d_out, int out_size, void* d_ws, size_t ws_size,
                              hipStream_t stream) {
    const float* x  = (const float*)d_in[0];
    const float* Wg = (const float*)d_in[1];
    const float* W1 = (const float*)d_in[2];
    const float* W3 = (const float*)d_in[3];
    const float* W2 = (const float*)d_in[4];
    const int N = in_sizes[0] / C;       // 2048 tokens
    const int nslots = N * 2;            // 4096

    float* y = (float*)d_out;
    float* out_idx = y + (size_t)N * C;

    char* ws = (char*)d_ws;
    size_t off = 0;
    auto alloc = [&](size_t bytes) { size_t p = off; off = (off + bytes + 255) & ~(size_t)255; return p; };
    float* probs   = (float*)(ws + alloc((size_t)nslots * 4));
    int* idxbuf    = (int*)(ws + alloc((size_t)nslots * 4));
    int* rowinfo   = (int*)(ws + alloc((size_t)nslots * 4));
    int* counts    = (int*)(ws + alloc(64));
    int* offs      = (int*)(ws + alloc(64));
    bf16_t* xb     = (bf16_t*)(ws + alloc((size_t)N * C * 2));
    bf16_t* hbuf   = (bf16_t*)(ws + alloc((size_t)nslots * F * 2));
    bf16_t* Wt1    = (bf16_t*)(ws + alloc((size_t)NE * C * F * 2));
    bf16_t* Wt3    = (bf16_t*)(ws + alloc((size_t)NE * C * F * 2));
    bf16_t* Wt2    = (bf16_t*)(ws + alloc((size_t)NE * C * F * 2));
    const size_t partbytes = (size_t)nslots * C * 4;
    int PK = 1;
    if (off + 4 * partbytes + 1024 <= ws_size) PK = 4;
    else if (off + 2 * partbytes + 1024 <= ws_size) PK = 2;
    float* part = (float*)(ws + alloc((size_t)PK * partbytes));

    const int mtiles = nslots / 128;     // worst-case m-tiles per expert

    router_kernel<<<N, 64, 0, stream>>>(x, Wg, probs, idxbuf, out_idx, xb);
    group_kernel<<<1, 256, 0, stream>>>(idxbuf, rowinfo, counts, offs, N);
    convert_kernel<<<dim3(704, 24), 256, 0, stream>>>(W1, W3, W2, Wt1, Wt3, Wt2);
    gemm1_kernel<<<dim3(F / 128, mtiles, NE), 256, 0, stream>>>(xb, Wt1, Wt3, rowinfo, counts, offs, hbuf);
    gemm2_kernel<<<dim3(C / 128, mtiles, NE * PK), 256, 0, stream>>>(hbuf, Wt2, rowinfo, counts, offs, part, PK, nslots);
    reduce_kernel<<<(N * C / 4 + 255) / 256, 256, 0, stream>>>(part, probs, y, PK, nslots);
}

// Round 3
// 451.872 us; speedup vs baseline: 1.1639x; 1.0075x over previous
//
#include <hip/hip_runtime.h>
#include <hip/hip_bf16.h>

#define NE 8
#define C 1024
#define F 2816

typedef __bf16 bf16_t;
typedef bf16_t bf16x8 __attribute__((ext_vector_type(8)));
typedef float f32x4 __attribute__((ext_vector_type(4)));

__device__ inline unsigned pk2(float a, float b) {
    union { bf16_t h[2]; unsigned u; } x;
    x.h[0] = (bf16_t)a; x.h[1] = (bf16_t)b;
    return x.u;
}

// async global->LDS, 16 B per lane; lds base must be wave-uniform
__device__ __forceinline__ void async_ld16(const bf16_t* g, bf16_t* l) {
    __builtin_amdgcn_global_load_lds(
        (const __attribute__((address_space(1))) unsigned int*)g,
        (__attribute__((address_space(3))) unsigned int*)l, 16, 0, 0);
}

// ---------------- router: fp32 logits, top-2, softmax; also emits bf16 x ----------------
__global__ void router_kernel(const float* __restrict__ x, const float* __restrict__ Wg,
                              float* __restrict__ probs, int* __restrict__ idxbuf,
                              float* __restrict__ out_idx, bf16_t* __restrict__ xb) {
    const int n = blockIdx.x;
    const int lane = threadIdx.x;  // 64 threads = 1 wave
    const float* xr = x + (size_t)n * C;
    bf16_t* xbr = xb + (size_t)n * C;
    float acc[NE] = {0.f, 0.f, 0.f, 0.f, 0.f, 0.f, 0.f, 0.f};
    #pragma unroll
    for (int i = 0; i < C / 64; i++) {
        int c = i * 64 + lane;
        float xv = xr[c];
        xbr[c] = (bf16_t)xv;
        const float4* w = (const float4*)(Wg + (size_t)c * NE);
        float4 w0 = w[0], w1 = w[1];
        acc[0] += xv * w0.x; acc[1] += xv * w0.y; acc[2] += xv * w0.z; acc[3] += xv * w0.w;
        acc[4] += xv * w1.x; acc[5] += xv * w1.y; acc[6] += xv * w1.z; acc[7] += xv * w1.w;
    }
    #pragma unroll
    for (int off = 32; off >= 1; off >>= 1)
        #pragma unroll
        for (int e = 0; e < NE; e++) acc[e] += __shfl_down(acc[e], off);
    if (lane == 0) {
        float v0 = -1e30f, v1 = -1e30f; int i0 = 0, i1 = 0;
        #pragma unroll
        for (int e = 0; e < NE; e++) {
            float v = acc[e];
            if (v > v0)      { v1 = v0; i1 = i0; v0 = v; i0 = e; }
            else if (v > v1) { v1 = v; i1 = e; }
        }
        float e1 = __expf(v1 - v0);
        probs[n * 2]     = 1.0f / (1.0f + e1);
        probs[n * 2 + 1] = e1 / (1.0f + e1);
        idxbuf[n * 2]     = i0;
        idxbuf[n * 2 + 1] = i1;
        out_idx[n * 2]     = (float)i0;
        out_idx[n * 2 + 1] = (float)i1;
    }
}

// ---------------- group tokens by expert (single block) ----------------
__global__ void group_kernel(const int* __restrict__ idxbuf, int* __restrict__ rowinfo,
                             int* __restrict__ counts, int* __restrict__ offs, int N) {
    __shared__ int cnt[NE], run[NE], base[NE];
    const int t = threadIdx.x;
    if (t < NE) { cnt[t] = 0; run[t] = 0; }
    __syncthreads();
    for (int i = t; i < N * 2; i += blockDim.x) atomicAdd(&cnt[idxbuf[i]], 1);
    __syncthreads();
    if (t == 0) { int s = 0; for (int e = 0; e < NE; e++) { base[e] = s; s += cnt[e]; } }
    __syncthreads();
    for (int i = t; i < N * 2; i += blockDim.x) {
        int e = idxbuf[i];
        int p = atomicAdd(&run[e], 1);
        rowinfo[base[e] + p] = i;          // i = n*2 + k
    }
    if (t < NE) { counts[t] = cnt[t]; offs[t] = base[t]; }
}

// ---------------- convert + transpose weights: fp32 [R][Cc] -> bf16 [Cc][R] ----------------
// LDS-free: each thread does an 8x8 register transpose.
__global__ __launch_bounds__(256)
void convert_kernel(const float* __restrict__ W1, const float* __restrict__ W3,
                    const float* __restrict__ W2, bf16_t* __restrict__ Wt1,
                    bf16_t* __restrict__ Wt3, bf16_t* __restrict__ Wt2) {
    const int yy = blockIdx.y;               // 24 = 3 mats x 8 experts
    const int which = yy >> 3, e = yy & 7;
    const float* src; bf16_t* dst; int R, Cc;
    if (which == 0)      { src = W1; dst = Wt1; R = C; Cc = F; }
    else if (which == 1) { src = W3; dst = Wt3; R = C; Cc = F; }
    else                 { src = W2; dst = Wt2; R = F; Cc = C; }
    src += (size_t)e * C * F;
    dst += (size_t)e * C * F;
    const int tiles_r = R >> 7;              // 128x128 tiles
    const int trb = blockIdx.x % tiles_r, tcb = blockIdx.x / tiles_r;
    const int t = threadIdx.x;
    const int R0 = trb * 128 + (t >> 4) * 8;   // row (input-major) of this thread's 8x8
    const int C0 = tcb * 128 + (t & 15) * 8;   // col

    const float* sp = src + (size_t)R0 * Cc + C0;
    float4 va[8], vb[8];
    #pragma unroll
    for (int i = 0; i < 8; i++) {
        va[i] = *(const float4*)(sp + (size_t)i * Cc);
        vb[i] = *(const float4*)(sp + (size_t)i * Cc + 4);
    }
    bf16_t* dp = dst + (size_t)C0 * R + R0;
    uint4 o;
    o.x = pk2(va[0].x, va[1].x); o.y = pk2(va[2].x, va[3].x); o.z = pk2(va[4].x, va[5].x); o.w = pk2(va[6].x, va[7].x);
    *(uint4*)(dp + 0 * (size_t)R) = o;
    o.x = pk2(va[0].y, va[1].y); o.y = pk2(va[2].y, va[3].y); o.z = pk2(va[4].y, va[5].y); o.w = pk2(va[6].y, va[7].y);
    *(uint4*)(dp + 1 * (size_t)R) = o;
    o.x = pk2(va[0].z, va[1].z); o.y = pk2(va[2].z, va[3].z); o.z = pk2(va[4].z, va[5].z); o.w = pk2(va[6].z, va[7].z);
    *(uint4*)(dp + 2 * (size_t)R) = o;
    o.x = pk2(va[0].w, va[1].w); o.y = pk2(va[2].w, va[3].w); o.z = pk2(va[4].w, va[5].w); o.w = pk2(va[6].w, va[7].w);
    *(uint4*)(dp + 3 * (size_t)R) = o;
    o.x = pk2(vb[0].x, vb[1].x); o.y = pk2(vb[2].x, vb[3].x); o.z = pk2(vb[4].x, vb[5].x); o.w = pk2(vb[6].x, vb[7].x);
    *(uint4*)(dp + 4 * (size_t)R) = o;
    o.x = pk2(vb[0].y, vb[1].y); o.y = pk2(vb[2].y, vb[3].y); o.z = pk2(vb[4].y, vb[5].y); o.w = pk2(vb[6].y, vb[7].y);
    *(uint4*)(dp + 5 * (size_t)R) = o;
    o.x = pk2(vb[0].z, vb[1].z); o.y = pk2(vb[2].z, vb[3].z); o.z = pk2(vb[4].z, vb[5].z); o.w = pk2(vb[6].z, vb[7].z);
    *(uint4*)(dp + 6 * (size_t)R) = o;
    o.x = pk2(vb[0].w, vb[1].w); o.y = pk2(vb[2].w, vb[3].w); o.z = pk2(vb[4].w, vb[5].w); o.w = pk2(vb[6].w, vb[7].w);
    *(uint4*)(dp + 7 * (size_t)R) = o;
}

// ---------------- GEMM1: h = silu(Xg@W1) * (Xg@W3), grouped per expert ----------------
__global__ __launch_bounds__(256, 2)
void gemm1_kernel(const bf16_t* __restrict__ xb, const bf16_t* __restrict__ Wt1,
                  const bf16_t* __restrict__ Wt3, const int* __restrict__ rowinfo,
                  const int* __restrict__ counts, const int* __restrict__ offs,
                  bf16_t* __restrict__ hbuf) {
    const int e = blockIdx.z;
    const int cnt = counts[e];
    const int m0 = blockIdx.y << 7;
    if (m0 >= cnt) return;
    const int base = offs[e];
    const int f0 = blockIdx.x << 7;
    const int t = threadIdx.x;
    const int lane = t & 63, w = t >> 6;
    const int lr = lane & 15, quad = lane >> 4;
    const int wm = (w >> 1) << 6, wn = (w & 1) << 6;

    __shared__ __align__(16) bf16_t As[128 * 32];
    __shared__ __align__(16) bf16_t B1s[128 * 32];
    __shared__ __align__(16) bf16_t B3s[128 * 32];

    const int srow = w * 16 + (lane >> 2);   // staging row within 64-row half
    const int skoff = (lane & 3) * 8;        // bf16 elems within 32-k chunk
    const int r0 = min(m0 + srow, cnt - 1);
    const int r1 = min(m0 + 64 + srow, cnt - 1);
    const bf16_t* ag0 = xb + (size_t)(rowinfo[base + r0] >> 1) * C + skoff;
    const bf16_t* ag1 = xb + (size_t)(rowinfo[base + r1] >> 1) * C + skoff;
    const bf16_t* b1g0 = Wt1 + ((size_t)e * F + f0 + srow) * C + skoff;
    const bf16_t* b1g1 = b1g0 + (size_t)64 * C;
    const bf16_t* b3g0 = Wt3 + ((size_t)e * F + f0 + srow) * C + skoff;
    const bf16_t* b3g1 = b3g0 + (size_t)64 * C;
    bf16_t* lA0 = &As[(w * 16) * 32];
    bf16_t* lA1 = &As[(64 + w * 16) * 32];
    bf16_t* lB10 = &B1s[(w * 16) * 32];
    bf16_t* lB11 = &B1s[(64 + w * 16) * 32];
    bf16_t* lB30 = &B3s[(w * 16) * 32];
    bf16_t* lB31 = &B3s[(64 + w * 16) * 32];

    f32x4 acc1[4][4], acc3[4][4];
    const f32x4 zero = {0.f, 0.f, 0.f, 0.f};
    #pragma unroll
    for (int im = 0; im < 4; im++)
        #pragma unroll
        for (int in = 0; in < 4; in++) { acc1[im][in] = zero; acc3[im][in] = zero; }

    for (int kc = 0; kc < C; kc += 32) {
        async_ld16(ag0 + kc, lA0);
        async_ld16(ag1 + kc, lA1);
        async_ld16(b1g0 + kc, lB10);
        async_ld16(b1g1 + kc, lB11);
        async_ld16(b3g0 + kc, lB30);
        async_ld16(b3g1 + kc, lB31);
        __syncthreads();
        bf16x8 af[4], b1f[4], b3f[4];
        #pragma unroll
        for (int im = 0; im < 4; im++)
            af[im] = *(const bf16x8*)(&As[(wm + im * 16 + lr) * 32 + quad * 8]);
        #pragma unroll
        for (int in = 0; in < 4; in++) {
            b1f[in] = *(const bf16x8*)(&B1s[(wn + in * 16 + lr) * 32 + quad * 8]);
            b3f[in] = *(const bf16x8*)(&B3s[(wn + in * 16 + lr) * 32 + quad * 8]);
        }
        #pragma unroll
        for (int im = 0; im < 4; im++)
            #pragma unroll
            for (int in = 0; in < 4; in++) {
                acc1[im][in] = __builtin_amdgcn_mfma_f32_16x16x32_bf16(af[im], b1f[in], acc1[im][in], 0, 0, 0);
                acc3[im][in] = __builtin_amdgcn_mfma_f32_16x16x32_bf16(af[im], b3f[in], acc3[im][in], 0, 0, 0);
            }
        __syncthreads();
    }
    #pragma unroll
    for (int im = 0; im < 4; im++) {
        #pragma unroll
        for (int r = 0; r < 4; r++) {
            const int row = wm + im * 16 + quad * 4 + r;
            const int gi = m0 + row;
            if (gi < cnt) {
                bf16_t* hp = hbuf + (size_t)(base + gi) * F + f0 + wn + lr;
                #pragma unroll
                for (int in = 0; in < 4; in++) {
                    float h1 = acc1[im][in][r], h3 = acc3[im][in][r];
                    float s = h1 / (1.0f + __expf(-h1)) * h3;
                    hp[in * 16] = (bf16_t)s;
                }
            }
        }
    }
}

// ---------------- GEMM2 (split-K): part[ks][slot] = h @ Wt2[e] over K-slice (bf16 partials) ----------------
__global__ __launch_bounds__(256, 2)
void gemm2_kernel(const bf16_t* __restrict__ hbuf, const bf16_t* __restrict__ Wt2,
                  const int* __restrict__ rowinfo, const int* __restrict__ counts,
                  const int* __restrict__ offs, bf16_t* __restrict__ part,
                  int PK, int nslots) {
    const int z = blockIdx.z;
    const int e = z & 7, ks = z >> 3;
    const int cnt = counts[e];
    const int m0 = blockIdx.y << 7;
    if (m0 >= cnt) return;
    const int base = offs[e];
    const int c0 = blockIdx.x << 7;
    const int t = threadIdx.x;
    const int lane = t & 63, w = t >> 6;
    const int lr = lane & 15, quad = lane >> 4;
    const int wm = (w >> 1) << 6, wn = (w & 1) << 6;

    const int klen = F / PK;
    const int kbeg = ks * klen, kend = kbeg + klen;

    __shared__ __align__(16) bf16_t As[128 * 32];
    __shared__ __align__(16) bf16_t Bs[128 * 32];

    const int srow = w * 16 + (lane >> 2);
    const int skoff = (lane & 3) * 8;
    const int r0 = min(m0 + srow, cnt - 1);
    const int r1 = min(m0 + 64 + srow, cnt - 1);
    const bf16_t* ag0 = hbuf + (size_t)(base + r0) * F + skoff;
    const bf16_t* ag1 = hbuf + (size_t)(base + r1) * F + skoff;
    const bf16_t* bg0 = Wt2 + ((size_t)e * C + c0 + srow) * F + skoff;
    const bf16_t* bg1 = bg0 + (size_t)64 * F;
    bf16_t* lA0 = &As[(w * 16) * 32];
    bf16_t* lA1 = &As[(64 + w * 16) * 32];
    bf16_t* lB0 = &Bs[(w * 16) * 32];
    bf16_t* lB1 = &Bs[(64 + w * 16) * 32];

    f32x4 acc[4][4];
    const f32x4 zero = {0.f, 0.f, 0.f, 0.f};
    #pragma unroll
    for (int im = 0; im < 4; im++)
        #pragma unroll
        for (int in = 0; in < 4; in++) acc[im][in] = zero;

    for (int kc = kbeg; kc < kend; kc += 32) {
        async_ld16(ag0 + kc, lA0);
        async_ld16(ag1 + kc, lA1);
        async_ld16(bg0 + kc, lB0);
        async_ld16(bg1 + kc, lB1);
        __syncthreads();
        bf16x8 af[4], bf_[4];
        #pragma unroll
        for (int im = 0; im < 4; im++)
            af[im] = *(const bf16x8*)(&As[(wm + im * 16 + lr) * 32 + quad * 8]);
        #pragma unroll
        for (int in = 0; in < 4; in++)
            bf_[in] = *(const bf16x8*)(&Bs[(wn + in * 16 + lr) * 32 + quad * 8]);
        #pragma unroll
        for (int im = 0; im < 4; im++)
            #pragma unroll
            for (int in = 0; in < 4; in++)
                acc[im][in] = __builtin_amdgcn_mfma_f32_16x16x32_bf16(af[im], bf_[in], acc[im][in], 0, 0, 0);
        __syncthreads();
    }
    #pragma unroll
    for (int im = 0; im < 4; im++) {
        #pragma unroll
        for (int r = 0; r < 4; r++) {
            const int row = wm + im * 16 + quad * 4 + r;
            const int gi = m0 + row;
            if (gi < cnt) {
                const int slot = rowinfo[base + gi];
                bf16_t* cp = part + ((size_t)ks * nslots + slot) * C + c0 + wn + lr;
                #pragma unroll
                for (int in = 0; in < 4; in++) cp[in * 16] = (bf16_t)acc[im][in][r];
            }
        }
    }
}

// ---------------- reduce partials + combine: y = p0*sum(part[.,2n]) + p1*sum(part[.,2n+1]) ----------------
__global__ void reduce_kernel(const bf16_t* __restrict__ part, const float* __restrict__ probs,
                              float* __restrict__ y, int PK, int nslots) {
    const int idx = blockIdx.x * blockDim.x + threadIdx.x;  // 8 elems per thread
    const int n = idx >> 7;           // C/8 = 128 chunks per row
    const int c = (idx & 127) * 8;
    const size_t ksstride = (size_t)nslots * C;
    const bf16_t* b0 = part + ((size_t)n * 2) * C + c;
    float s0[8] = {0, 0, 0, 0, 0, 0, 0, 0}, s1[8] = {0, 0, 0, 0, 0, 0, 0, 0};
    for (int ks = 0; ks < PK; ks++) {
        bf16x8 a = *(const bf16x8*)(b0 + ks * ksstride);
        bf16x8 b = *(const bf16x8*)(b0 + ks * ksstride + C);
        #pragma unroll
        for (int i = 0; i < 8; i++) { s0[i] += (float)a[i]; s1[i] += (float)b[i]; }
    }
    const float p0 = probs[n * 2], p1 = probs[n * 2 + 1];
    float4 o0, o1;
    o0.x = p0 * s0[0] + p1 * s1[0];
    o0.y = p0 * s0[1] + p1 * s1[1];
    o0.z = p0 * s0[2] + p1 * s1[2];
    o0.w = p0 * s0[3] + p1 * s1[3];
    o1.x = p0 * s0[4] + p1 * s1[4];
    o1.y = p0 * s0[5] + p1 * s1[5];
    o1.z = p0 * s0[6] + p1 * s1[6];
    o1.w = p0 * s0[7] + p1 * s1[7];
    *(float4*)(y + (size_t)n * C + c) = o0;
    *(float4*)(y + (size_t)n * C + c + 4) = o1;
}

extern "C" void kernel_launch(void* const* d_in, const int* in_sizes, int n_in,
                              void* d_out, int out_size, void* d_ws, size_t ws_size,
                              hipStream_t stream) {
    const float* x  = (const float*)d_in[0];
    const float* Wg = (const float*)d_in[1];
    const float* W1 = (const float*)d_in[2];
    const float* W3 = (const float*)d_in[3];
    const float* W2 = (const float*)d_in[4];
    const int N = in_sizes[0] / C;       // 2048 tokens
    const int nslots = N * 2;            // 4096

    float* y = (float*)d_out;
    float* out_idx = y + (size_t)N * C;

    char* ws = (char*)d_ws;
    size_t off = 0;
    auto alloc = [&](size_t bytes) { size_t p = off; off = (off + bytes + 255) & ~(size_t)255; return p; };
    float* probs   = (float*)(ws + alloc((size_t)nslots * 4));
    int* idxbuf    = (int*)(ws + alloc((size_t)nslots * 4));
    int* rowinfo   = (int*)(ws + alloc((size_t)nslots * 4));
    int* counts    = (int*)(ws + alloc(64));
    int* offs      = (int*)(ws + alloc(64));
    bf16_t* xb     = (bf16_t*)(ws + alloc((size_t)N * C * 2));
    bf16_t* hbuf   = (bf16_t*)(ws + alloc((size_t)nslots * F * 2));
    bf16_t* Wt1    = (bf16_t*)(ws + alloc((size_t)NE * C * F * 2));
    bf16_t* Wt3    = (bf16_t*)(ws + alloc((size_t)NE * C * F * 2));
    bf16_t* Wt2    = (bf16_t*)(ws + alloc((size_t)NE * C * F * 2));
    const size_t partbytes = (size_t)nslots * C * 2;  // bf16 partials
    int PK = 1;
    if (off + 4 * partbytes + 1024 <= ws_size) PK = 4;
    else if (off + 2 * partbytes + 1024 <= ws_size) PK = 2;
    bf16_t* part = (bf16_t*)(ws + alloc((size_t)PK * partbytes));

    const int mtiles = nslots / 128;     // worst-case m-tiles per expert

    router_kernel<<<N, 64, 0, stream>>>(x, Wg, probs, idxbuf, out_idx, xb);
    group_kernel<<<1, 256, 0, stream>>>(idxbuf, rowinfo, counts, offs, N);
    convert_kernel<<<dim3(176, 24), 256, 0, stream>>>(W1, W3, W2, Wt1, Wt3, Wt2);
    gemm1_kernel<<<dim3(F / 128, mtiles, NE), 256, 0, stream>>>(xb, Wt1, Wt3, rowinfo, counts, offs, hbuf);
    gemm2_kernel<<<dim3(C / 128, mtiles, NE * PK), 256, 0, stream>>>(hbuf, Wt2, rowinfo, counts, offs, part, PK, nslots);
    reduce_kernel<<<(N * C / 8 + 255) / 256, 256, 0, stream>>>(part, probs, y, PK, nslots);
}